// Round 14
// baseline (242.752 us; speedup 1.0000x reference)
//
#include <hip/hip_runtime.h>

#define NUM_USERS  150000
#define NUM_ITEMS  140000
#define NUM_BRANDS 10000
#define N_NODES    300000
#define DIM        64
#define N_EDGES    1200000
#define OUT_ROWS   290000          // users + items

#define CHUNK      1024            // elements per scan block
#define NB         ((N_NODES + CHUNK - 1) / CHUNK)   // 293 scan blocks

#define NBIN       8               // one bin per XCD
#define BINSZ      (N_EDGES / NBIN)                  // 150000 csr records/bin

// ---------------------------------------------------------------------------
// bf16 helpers (h1/h2 stored as packed bf16: 64 dims = 8 uint4 per row)
// ---------------------------------------------------------------------------
__device__ __forceinline__ float bf_lo(unsigned u) { return __uint_as_float(u << 16); }
__device__ __forceinline__ float bf_hi(unsigned u) { return __uint_as_float(u & 0xffff0000u); }
__device__ __forceinline__ unsigned pack_bf(float a, float b) {
    unsigned ua = __float_as_uint(a); ua += 0x7fffu + ((ua >> 16) & 1u);
    unsigned ub = __float_as_uint(b); ub += 0x7fffu + ((ub >> 16) & 1u);
    return (ua >> 16) | (ub & 0xffff0000u);
}

// ---------------------------------------------------------------------------
// histogram of destination degrees + per-edge rank within its row
// ---------------------------------------------------------------------------
__global__ void lgcn_hist(const int* __restrict__ dst,
                          int* __restrict__ counts,
                          int* __restrict__ rank) {
    int e = blockIdx.x * blockDim.x + threadIdx.x;
    if (e >= N_EDGES) return;
    rank[e] = atomicAdd(&counts[dst[e]], 1);
}

// ---------------------------------------------------------------------------
// scan phase 1: per-1024-chunk exclusive scan (256 thr x 4 elem), chunk sums
// ---------------------------------------------------------------------------
__global__ void lgcn_scan_p1(const int* __restrict__ counts,
                             int* __restrict__ rowptr,
                             int* __restrict__ blockSums) {
    __shared__ int ts[256];
    int b    = blockIdx.x;
    int base = b * CHUNK;
    int t    = threadIdx.x;
    int c[4];
    int s = 0;
#pragma unroll
    for (int i = 0; i < 4; ++i) {
        int g = base + t * 4 + i;
        c[i] = (g < N_NODES) ? counts[g] : 0;
        s += c[i];
    }
    ts[t] = s;
    __syncthreads();
    for (int off = 1; off < 256; off <<= 1) {
        int v = (t >= off) ? ts[t - off] : 0;
        __syncthreads();
        ts[t] += v;
        __syncthreads();
    }
    int run = ts[t] - s;     // exclusive prefix of this thread's 4-group
#pragma unroll
    for (int i = 0; i < 4; ++i) {
        int g = base + t * 4 + i;
        if (g < N_NODES) rowptr[g] = run;
        run += c[i];
    }
    if (t == 255) blockSums[b] = ts[255];
}

// ---------------------------------------------------------------------------
// scan phase 2: single block exclusive-scans the NB (=293) chunk sums
// ---------------------------------------------------------------------------
__global__ void lgcn_scan_p2(int* __restrict__ blockSums) {
    __shared__ int sh[512];
    int t = threadIdx.x;
    int v = (t < NB) ? blockSums[t] : 0;
    sh[t] = v;
    __syncthreads();
    for (int off = 1; off < 512; off <<= 1) {
        int u = (t >= off) ? sh[t - off] : 0;
        __syncthreads();
        sh[t] += u;
        __syncthreads();
    }
    if (t < NB) blockSums[t] = sh[t] - v;   // exclusive
}

// ---------------------------------------------------------------------------
// scan phase 3: add chunk offsets; rowptr[N_NODES] = N_EDGES
// ---------------------------------------------------------------------------
__global__ void lgcn_scan_p3(int* __restrict__ rowptr,
                             const int* __restrict__ blockSums) {
    int b    = blockIdx.x;
    int base = b * CHUNK;
    int t    = threadIdx.x;
    int off  = blockSums[b];
#pragma unroll
    for (int i = 0; i < 4; ++i) {
        int g = base + t * 4 + i;
        if (g < N_NODES) rowptr[g] += off;
    }
    if (b == 0 && t == 0) rowptr[N_NODES] = N_EDGES;
}

// ---------------------------------------------------------------------------
// pos precompute: one pass so the 8 binned passes re-read only pos (4.8MB)
// (R11/R13 evidence: cuts csr_bin to ~14us vs ~65 fused)
// ---------------------------------------------------------------------------
__global__ void lgcn_pos(const int* __restrict__ dst,
                         const int* __restrict__ rank,
                         const int* __restrict__ rowptr,
                         int* __restrict__ pos) {
    int e = blockIdx.x * blockDim.x + threadIdx.x;
    if (e >= N_EDGES) return;
    pos[e] = rowptr[dst[e]] + rank[e];
}

// ---------------------------------------------------------------------------
// XCD-private binned CSR build: block b handles edge chunk (b>>3), position
// bin (b&7). blockIdx%8 -> XCD, so each bin's csr lines are dirtied by one
// XCD's L2 and mostly evict full.
// ---------------------------------------------------------------------------
__global__ void lgcn_csr_bin(const int*   __restrict__ src,
                             const float* __restrict__ vals,
                             const int*   __restrict__ pos,
                             uint2*       __restrict__ csr) {
    int b    = blockIdx.x;
    int bin  = b & (NBIN - 1);
    int e    = (b >> 3) * blockDim.x + threadIdx.x;
    if (e >= N_EDGES) return;
    int p  = pos[e];
    int lo = bin * BINSZ;
    if (p >= lo && p < lo + BINSZ) {
        csr[p] = make_uint2((unsigned)src[e], __float_as_uint(vals[e]));
    }
}

// ---------------------------------------------------------------------------
// fp32 ego row lookup: concat(user,item,brand) without materializing it
// ---------------------------------------------------------------------------
__device__ __forceinline__ const float4* ego_row(const float* __restrict__ user,
                                                 const float* __restrict__ item,
                                                 const float* __restrict__ brand,
                                                 int r) {
    if (r < NUM_USERS)
        return reinterpret_cast<const float4*>(user) + (r << 4);
    else if (r < NUM_USERS + NUM_ITEMS)
        return reinterpret_cast<const float4*>(item) + ((r - NUM_USERS) << 4);
    else
        return reinterpret_cast<const float4*>(brand) + ((r - NUM_USERS - NUM_ITEMS) << 4);
}

// ---------------------------------------------------------------------------
// Row storage trait: LAYER 1 reads fp32 ego rows (2x float4 per lane);
// LAYER 2/3 read raw bf16 words (1x uint4 per lane), unpacked only at the
// fma (so the compiler's waitcnt tracks the oldest outstanding load).
// ---------------------------------------------------------------------------
template <int LAYER>
struct RowStore {
    typedef uint4 type;
    static __device__ __forceinline__ type load(const uint4* __restrict__ h,
                                                const float*, const float*, const float*,
                                                int r, int q) {
        return h[(r << 3) + q];
    }
    static __device__ __forceinline__ void fma(float4& s0, float4& s1, type w, float v) {
        s0.x = fmaf(bf_lo(w.x), v, s0.x);
        s0.y = fmaf(bf_hi(w.x), v, s0.y);
        s0.z = fmaf(bf_lo(w.y), v, s0.z);
        s0.w = fmaf(bf_hi(w.y), v, s0.w);
        s1.x = fmaf(bf_lo(w.z), v, s1.x);
        s1.y = fmaf(bf_hi(w.z), v, s1.y);
        s1.z = fmaf(bf_lo(w.w), v, s1.z);
        s1.w = fmaf(bf_hi(w.w), v, s1.w);
    }
};

struct Row8 { float4 a, b; };
template <>
struct RowStore<1> {
    typedef Row8 type;
    static __device__ __forceinline__ type load(const uint4*,
                                                const float* __restrict__ u,
                                                const float* __restrict__ i,
                                                const float* __restrict__ b,
                                                int r, int q) {
        const float4* er = ego_row(u, i, b, r);
        Row8 t;
        t.a = er[2 * q];
        t.b = er[2 * q + 1];
        return t;
    }
    static __device__ __forceinline__ void fma(float4& s0, float4& s1, type w, float v) {
        s0.x = fmaf(w.a.x, v, s0.x);
        s0.y = fmaf(w.a.y, v, s0.y);
        s0.z = fmaf(w.a.z, v, s0.z);
        s0.w = fmaf(w.a.w, v, s0.w);
        s1.x = fmaf(w.b.x, v, s1.x);
        s1.y = fmaf(w.b.y, v, s1.y);
        s1.z = fmaf(w.b.z, v, s1.z);
        s1.w = fmaf(w.b.w, v, s1.w);
    }
};

// ---------------------------------------------------------------------------
// gather SpMM: 8 lanes per dst node (8 dims/lane), 8 nodes per wave.
// R12's plain 4-deep pipeline (measured best ~57us; the R13 x2-unroll
// regressed to 65 via redundant clamped loads + VGPR growth — reverted).
// Recs prefetched 4 ahead, rows staged 3 deep as raw words.
// LAYER=1: ego(fp32)->h1(bf16). LAYER=2: h1->h2. LAYER=3: h2 -> fused
// out = (ego + h1 + h2 + sum) * 0.25.
// ---------------------------------------------------------------------------
template <int LAYER>
__global__ void lgcn_gather(const int*   __restrict__ rowptr,
                            const uint2* __restrict__ csr,
                            const uint4* __restrict__ h_src,
                            const float* __restrict__ user,
                            const float* __restrict__ item,
                            const float* __restrict__ brand,
                            const uint4* __restrict__ h1,
                            const uint4* __restrict__ h2,
                            uint4*       __restrict__ h_out,
                            float*       __restrict__ out) {
    typedef typename RowStore<LAYER>::type RowT;
    int g    = blockIdx.x * blockDim.x + threadIdx.x;   // node*8 + q
    int node = g >> 3;
    int q    = g & 7;
    int beg = rowptr[node];
    int end = rowptr[node + 1];
    float4 s0 = make_float4(0.f, 0.f, 0.f, 0.f);
    float4 s1 = make_float4(0.f, 0.f, 0.f, 0.f);
    if (beg < end) {
        int last = end - 1;
        uint2 r0 = csr[beg];
        uint2 r1 = csr[beg + 1 < end ? beg + 1 : last];
        uint2 r2 = csr[beg + 2 < end ? beg + 2 : last];
        uint2 r3 = csr[beg + 3 < end ? beg + 3 : last];
        RowT w0 = RowStore<LAYER>::load(h_src, user, item, brand, (int)r0.x, q);
        RowT w1 = RowStore<LAYER>::load(h_src, user, item, brand, (int)r1.x, q);
        RowT w2 = RowStore<LAYER>::load(h_src, user, item, brand, (int)r2.x, q);
        for (int j = beg; j < end; ++j) {
            int jn = j + 4 < end ? j + 4 : last;
            uint2 r4 = csr[jn];                         // rec, 4 ahead
            RowT w3 = RowStore<LAYER>::load(h_src, user, item, brand, (int)r3.x, q);
            float v = __uint_as_float(r0.y);
            RowStore<LAYER>::fma(s0, s1, w0, v);
            r0 = r1; r1 = r2; r2 = r3; r3 = r4;
            w0 = w1; w1 = w2; w2 = w3;
        }
    }
    if (LAYER != 3) {
        uint4 w;
        w.x = pack_bf(s0.x, s0.y);
        w.y = pack_bf(s0.z, s0.w);
        w.z = pack_bf(s1.x, s1.y);
        w.w = pack_bf(s1.z, s1.w);
        h_out[g] = w;
    } else if (node < OUT_ROWS) {
        const float4* er = ego_row(user, item, brand, node);
        float4 e0 = er[2 * q];
        float4 e1 = er[2 * q + 1];
        uint4 w1 = h1[g];
        uint4 w2 = h2[g];
        float4 o0, o1;
        o0.x = (e0.x + bf_lo(w1.x) + bf_lo(w2.x) + s0.x) * 0.25f;
        o0.y = (e0.y + bf_hi(w1.x) + bf_hi(w2.x) + s0.y) * 0.25f;
        o0.z = (e0.z + bf_lo(w1.y) + bf_lo(w2.y) + s0.z) * 0.25f;
        o0.w = (e0.w + bf_hi(w1.y) + bf_hi(w2.y) + s0.w) * 0.25f;
        o1.x = (e1.x + bf_lo(w1.z) + bf_lo(w2.z) + s1.x) * 0.25f;
        o1.y = (e1.y + bf_hi(w1.z) + bf_hi(w2.z) + s1.y) * 0.25f;
        o1.z = (e1.z + bf_lo(w1.w) + bf_lo(w2.w) + s1.z) * 0.25f;
        o1.w = (e1.w + bf_hi(w1.w) + bf_hi(w2.w) + s1.w) * 0.25f;
        float4* o = reinterpret_cast<float4*>(out) + g * 2;
        o[0] = o0;
        o[1] = o1;
    }
}

extern "C" void kernel_launch(void* const* d_in, const int* in_sizes, int n_in,
                              void* d_out, int out_size, void* d_ws, size_t ws_size,
                              hipStream_t stream) {
    const float* user  = (const float*)d_in[0];
    const float* item  = (const float*)d_in[1];
    const float* brand = (const float*)d_in[2];
    const float* vals  = (const float*)d_in[3];
    const int*   src   = (const int*)d_in[4];
    const int*   dst   = (const int*)d_in[5];
    float* out = (float*)d_out;

    // workspace layout (32-bit words); 16B alignment holds for uint4 arrays
    size_t W = 0;
    uint4* h1  = (uint4*)d_ws;                 W += (size_t)N_NODES * 32;   // bf16 rows (128B)
    uint4* h2  = (uint4*)((int*)d_ws + W);     W += (size_t)N_NODES * 32;
    uint2* csr = (uint2*)((int*)d_ws + W);     W += (size_t)N_EDGES * 2;
    int* rank      = (int*)d_ws + W;           W += N_EDGES;
    int* pos       = (int*)d_ws + W;           W += N_EDGES;
    int* rowptr    = (int*)d_ws + W;           W += N_NODES + 2;
    int* counts    = (int*)d_ws + W;           W += N_NODES;       // memset
    int* blockSums = (int*)d_ws + W;           W += 512;
    (void)ws_size; (void)n_in; (void)in_sizes; (void)out_size;

    const int edgeBlocks   = (N_EDGES + 255) / 256;     // 4688
    const int gatherBlocks = (N_NODES * 8) / 256;       // 9375 (8 thr/node)

    // zero degree counters (workspace is poisoned; hist accumulates)
    hipMemsetAsync(counts, 0, (size_t)N_NODES * sizeof(int), stream);

    // build dst-sorted CSR: hist+rank -> scan -> pos -> XCD-binned scatter
    lgcn_hist   <<<edgeBlocks, 256, 0, stream>>>(dst, counts, rank);
    lgcn_scan_p1<<<NB, 256, 0, stream>>>(counts, rowptr, blockSums);
    lgcn_scan_p2<<<1, 512, 0, stream>>>(blockSums);
    lgcn_scan_p3<<<NB, 256, 0, stream>>>(rowptr, blockSums);
    lgcn_pos    <<<edgeBlocks, 256, 0, stream>>>(dst, rank, rowptr, pos);
    lgcn_csr_bin<<<NBIN * edgeBlocks, 256, 0, stream>>>(src, vals, pos, csr);

    // 3 atomic-free SpMM layers (bf16 intermediates); residual fused in L3
    lgcn_gather<1><<<gatherBlocks, 256, 0, stream>>>(rowptr, csr, nullptr, user, item,
                                                     brand, h1, h2, h1, out);
    lgcn_gather<2><<<gatherBlocks, 256, 0, stream>>>(rowptr, csr, h1, user, item,
                                                     brand, h1, h2, h2, out);
    lgcn_gather<3><<<gatherBlocks, 256, 0, stream>>>(rowptr, csr, h2, user, item,
                                                     brand, h1, h2, nullptr, out);
}